// Round 16
// baseline (800.952 us; speedup 1.0000x reference)
//
#include <hip/hip_runtime.h>
#include <hip/hip_bf16.h>

#define NB 16
#define DDIM 768
#define HH 28
#define WWID 28
#define NP 784
#define NTOT 12544
#define MTOT 16384
#define OUTHW 224

typedef __attribute__((ext_vector_type(8))) short bf16x8;
typedef __attribute__((ext_vector_type(4))) float f32x4;
typedef unsigned long long u64;

__device__ inline u64 packmin(float v, int idx) {
  unsigned u = __float_as_uint(v);
  u = (u & 0x80000000u) ? ~u : (u | 0x80000000u);
  return ((u64)u << 32) | (unsigned)idx;
}

__device__ inline void gload16(const void* g, void* l) {
  __builtin_amdgcn_global_load_lds((const __attribute__((address_space(1))) unsigned int*)g,
                                   (__attribute__((address_space(3))) unsigned int*)l, 16, 0, 0);
}

// ---------- avgpool3x3 + transpose to [N,D] + fp32 & bf16 ----------
__global__ void k_prep_emb(const float* __restrict__ feat, float* __restrict__ emb,
                           __hip_bfloat16* __restrict__ embh) {
  const int dt = blockIdx.x;   // 12
  const int ht = blockIdx.y;   // 7
  const int b  = blockIdx.z;   // 16
  const int d0 = dt * 64;
  const int h0 = ht * 4;
  const int n0 = b * NP + ht * 112;
  __shared__ float halo[64][169];
  const int t = threadIdx.x;
  for (int idx = t; idx < 64 * 168; idx += 256) {
    int dd = idx / 168, p = idx % 168;
    int rr = p / 28, w = p % 28;
    int h = h0 - 1 + rr;
    float v = 0.f;
    if (h >= 0 && h < HH)
      v = feat[(((size_t)b * DDIM + d0 + dd) * HH + h) * WWID + w];
    halo[dd][p] = v;
  }
  __syncthreads();
  for (int idx = t; idx < 112 * 64; idx += 256) {
    int nn = idx >> 6, dd = idx & 63;
    int hl = nn / 28, w = nn % 28;
    float s = 0.f;
#pragma unroll
    for (int dr = 0; dr < 3; ++dr) {
      const float* row = &halo[dd][(hl + dr) * 28];
      float c = row[w];
      if (w > 0) c += row[w - 1];
      if (w < 27) c += row[w + 1];
      s += c;
    }
    float v = s * (1.f / 9.f);
    size_t o = (size_t)(n0 + nn) * DDIM + d0 + dd;
    emb[o] = v;
    embh[o] = __float2bfloat16(v);
  }
}

// ---------- memory bank: bf16 + norms (+ rowmin/wrm/wmax init folded in) ----------
__global__ void k_prep_mb(const float* __restrict__ mb, __hip_bfloat16* __restrict__ mbh,
                          float* __restrict__ b2, u64* __restrict__ rowmin,
                          u64* __restrict__ wrm, u64* __restrict__ wmax) {
  int m = blockIdx.x, t = threadIdx.x;
  if (t == 0 && m < NTOT) rowmin[m] = ~0ull;
  if (t == 0 && m < NB) { wrm[m] = ~0ull; wmax[m] = 0ull; }
  const float* r = mb + (size_t)m * DDIM;
  float s = 0.f;
#pragma unroll
  for (int j = 0; j < 3; ++j) {
    float v = r[t + j * 256];
    s += v * v;
    mbh[(size_t)m * DDIM + t + j * 256] = __float2bfloat16(v);
  }
  for (int o = 32; o; o >>= 1) s += __shfl_down(s, o);
  __shared__ float ws4[4];
  if ((t & 63) == 0) ws4[t >> 6] = s;
  __syncthreads();
  if (t == 0) b2[m] = ws4[0] + ws4[1] + ws4[2] + ws4[3];
}

// ============ GEMM: R13 verbatim — 128x128, BK=32, single-buffer, 2 syncs,
// ============ coalesced staging, in-row XOR swizzle (0 conflicts), 14 waves/CU.
__global__ __launch_bounds__(256) void k_gemm(const __hip_bfloat16* __restrict__ A,
                                              const __hip_bfloat16* __restrict__ Bm,
                                              const float* __restrict__ b2,
                                              u64* __restrict__ rowmin) {
  __shared__ short As[128 * 32];
  __shared__ short Bs[128 * 32];
  __shared__ u64 rmin[128][2];
  const int t = threadIdx.x;
  const int m0 = blockIdx.x * 128;
  const int n0 = blockIdx.y * 128;
  const int w = t >> 6, l = t & 63;
  const int wr = w >> 1, wc = w & 1;
  const int lc = l & 15, lg = l >> 4;
  const int swz = lg ^ ((lc >> 1) & 3);   // fragment-read slot column

  const int s0 = t, s1 = t + 256;
  const int row0 = s0 >> 2, ko0 = (s0 & 3) ^ ((row0 >> 1) & 3);
  const int row1 = s1 >> 2, ko1 = (s1 & 3) ^ ((row1 >> 1) & 3);
  const __hip_bfloat16* Asrc0 = A + (size_t)(n0 + row0) * DDIM + ko0 * 8;
  const __hip_bfloat16* Asrc1 = A + (size_t)(n0 + row1) * DDIM + ko1 * 8;
  const __hip_bfloat16* Bsrc0 = Bm + (size_t)(m0 + row0) * DDIM + ko0 * 8;
  const __hip_bfloat16* Bsrc1 = Bm + (size_t)(m0 + row1) * DDIM + ko1 * 8;

  f32x4 acc[4][4] = {};
  for (int kt = 0; kt < 24; ++kt) {
    const int k0 = kt * 32;
    __syncthreads();
    gload16(Asrc0 + k0, (char*)As + s0 * 16);
    gload16(Bsrc0 + k0, (char*)Bs + s0 * 16);
    gload16(Asrc1 + k0, (char*)As + s1 * 16);
    gload16(Bsrc1 + k0, (char*)Bs + s1 * 16);
    __syncthreads();
    bf16x8 av[4], bv[4];
#pragma unroll
    for (int i = 0; i < 4; ++i) {
      av[i] = *(const bf16x8*)(As + (wr * 64 + i * 16 + lc) * 32 + swz * 8);
      bv[i] = *(const bf16x8*)(Bs + (wc * 64 + i * 16 + lc) * 32 + swz * 8);
    }
#pragma unroll
    for (int i = 0; i < 4; ++i)
#pragma unroll
      for (int j = 0; j < 4; ++j)
        acc[i][j] = __builtin_amdgcn_mfma_f32_16x16x32_bf16(av[i], bv[j], acc[i][j], 0, 0, 0);
  }
  __syncthreads();
  float b2v[4];
#pragma unroll
  for (int j = 0; j < 4; ++j) b2v[j] = b2[m0 + wc * 64 + j * 16 + lc];
#pragma unroll
  for (int i = 0; i < 4; ++i)
#pragma unroll
    for (int r = 0; r < 4; ++r) {
      u64 best = ~0ull;
#pragma unroll
      for (int j = 0; j < 4; ++j) {
        int col = m0 + wc * 64 + j * 16 + lc;
        float v = b2v[j] - 2.f * acc[i][j][r];
        u64 p = packmin(v, col);
        best = best < p ? best : p;
      }
#pragma unroll
      for (int o = 1; o < 16; o <<= 1) {
        u64 o2 = (u64)__shfl_xor((long long)best, o);
        best = best < o2 ? best : o2;
      }
      if (lc == 0) rmin[wr * 64 + i * 16 + lg * 4 + r][wc] = best;
    }
  __syncthreads();
  if (t < 128) {
    u64 b0 = rmin[t][0], b1 = rmin[t][1];
    u64 mm = b0 < b1 ? b0 : b1;
    atomicMin(&rowmin[n0 + t], mm);
  }
}

// ---------- exact fp32 repair + fused per-batch argmax (packed atomicMax) ----------
// pack = (bits(score) << 32) | (~n): higher score wins; on equal score the SMALLER n
// wins (matches jnp.argmax first-occurrence).
__global__ void k_fixrow(const u64* __restrict__ rowmin, const float* __restrict__ emb,
                         const float* __restrict__ mbf, float* __restrict__ ps,
                         u64* __restrict__ wmax) {
  int n = blockIdx.x * 4 + (threadIdx.x >> 6);
  int lane = threadIdx.x & 63;
  int col = (int)(rowmin[n] & 0xffffffffu);
  const float* e = emb + (size_t)n * DDIM;
  const float* m = mbf + (size_t)col * DDIM;
  float s = 0.f;
#pragma unroll
  for (int j = lane; j < DDIM; j += 64) { float d = e[j] - m[j]; s += d * d; }
  for (int o = 32; o; o >>= 1) s += __shfl_down(s, o);
  if (lane == 0) {
    float psv = sqrtf(s);
    ps[n] = psv;
    int b = n / NP;
    u64 pk = ((u64)__float_as_uint(psv) << 32) | (u64)(0xffffffffu - (unsigned)n);
    atomicMax(&wmax[b], pk);
  }
}

__device__ inline int decode_wn(u64 pk) { return (int)(0xffffffffu - (unsigned)(pk & 0xffffffffu)); }

// ---------- 16 query rows vs all M, fp32, padded-LDS (conflict-free) ----------
template <int MODE>
__global__ void k_dist16(const float* __restrict__ mbf, const float* __restrict__ emb,
                         const u64* __restrict__ wmax, const u64* __restrict__ wrm_in,
                         const float* __restrict__ b2,
                         u64* __restrict__ wrm_out, float* __restrict__ d2nn) {
  __shared__ float qr[16][66];
  __shared__ float mr[16][65];
  __shared__ int qi[16];
  int t = threadIdx.x;
  int m0 = blockIdx.x * 16;
  if (t < 16) qi[t] = (MODE == 0) ? decode_wn(wmax[t]) : (int)(wrm_in[t] & 0xffffffffu);
  __syncthreads();
  int b = t >> 4, mi = t & 15;
  float acc = 0.f;
  const float* qsrc = (MODE == 0) ? emb : mbf;
  for (int k0 = 0; k0 < DDIM; k0 += 64) {
    __syncthreads();
    for (int i = t; i < 1024; i += 256) {
      int r = i >> 6, kk = i & 63;
      qr[r][kk] = qsrc[(size_t)qi[r] * DDIM + k0 + kk];
      mr[r][kk] = mbf[(size_t)(m0 + r) * DDIM + k0 + kk];
    }
    __syncthreads();
#pragma unroll
    for (int kk = 0; kk < 64; ++kk) acc += qr[b][kk] * mr[mi][kk];
  }
  int m = m0 + mi;
  if (MODE == 0) {
    u64 p = packmin(b2[m] - 2.f * acc, m);
#pragma unroll
    for (int o = 1; o < 16; o <<= 1) {
      u64 o2 = (u64)__shfl_xor((long long)p, o);
      p = p < o2 ? p : o2;
    }
    if (mi == 0) atomicMin(&wrm_out[b], p);
  } else {
    d2nn[(size_t)b * MTOT + m] = b2[qi[b]] + b2[m] - 2.f * acc;
  }
}

// ---------- top-9 nearest + anomaly score (fused, register-cached row) ----------
__global__ void k_top9anom(const float* __restrict__ d2nn, const float* __restrict__ emb,
                           const float* __restrict__ mbf, const u64* __restrict__ wmax,
                           const float* __restrict__ ps, float* __restrict__ out_anom) {
  int b = blockIdx.x, t = threadIdx.x;
  const float* row = d2nn + (size_t)b * MTOT;
  float rvreg[64];
#pragma unroll
  for (int it = 0; it < 64; ++it) rvreg[it] = row[t + it * 256];
  __shared__ u64 red[256];
  __shared__ int chosen[9];
  for (int k = 0; k < 9; ++k) {
    u64 best = ~0ull;
#pragma unroll
    for (int it = 0; it < 64; ++it) {
      int m = t + it * 256;
      bool skip = false;
      for (int j = 0; j < k; ++j)
        if (chosen[j] == m) skip = true;
      if (!skip) {
        u64 p = packmin(rvreg[it], m);
        best = best < p ? best : p;
      }
    }
    red[t] = best; __syncthreads();
    for (int s = 128; s; s >>= 1) {
      if (t < s) red[t] = red[t] < red[t + s] ? red[t] : red[t + s];
      __syncthreads();
    }
    if (t == 0) chosen[k] = (int)(red[0] & 0xffffffffu);
    __syncthreads();
  }
  int wn = decode_wn(wmax[b]);
  __shared__ float er[DDIM];
  __shared__ float dist[9];
  __shared__ float fred[256];
  for (int j = t; j < DDIM; j += 256) er[j] = emb[(size_t)wn * DDIM + j];
  __syncthreads();
  for (int k = 0; k < 9; ++k) {
    const float* mr = mbf + (size_t)chosen[k] * DDIM;
    float s = 0.f;
    for (int j = t; j < DDIM; j += 256) { float d = er[j] - mr[j]; s += d * d; }
    fred[t] = s; __syncthreads();
    for (int st = 128; st; st >>= 1) { if (t < st) fred[t] += fred[t + st]; __syncthreads(); }
    if (t == 0) dist[k] = sqrtf(fmaxf(fred[0], 0.f));
    __syncthreads();
  }
  if (t == 0) {
    float mx = dist[0];
    for (int k = 1; k < 9; ++k) mx = fmaxf(mx, dist[k]);
    float sum = 0.f;
    for (int k = 0; k < 9; ++k) sum += expf(dist[k] - mx);
    float w = 1.f - expf(dist[0] - mx) / sum;
    out_anom[b] = w * ps[wn];
  }
}

__device__ inline void gauss_coefs(float* g, int t) {
  if (t == 0) {
    float tmp[33]; float s = 0.f;
    for (int j = 0; j < 33; ++j) { float c = (float)(j - 16); tmp[j] = expf(-(c * c) / 32.f); s += tmp[j]; }
    for (int j = 0; j < 33; ++j) g[j] = tmp[j] / s;
  }
}

// ---------- fused bilinear 28->224 (row) + horizontal gaussian blur ----------
__global__ void k_bh(const float* __restrict__ ps, float* __restrict__ out) {
  int by = blockIdx.x;  // b*224 + y
  int b = by / OUTHW, y = by % OUTHW;
  int t = threadIdx.x;
  __shared__ float g[33];
  __shared__ float rowbuf[OUTHW];
  gauss_coefs(g, t);
  float sy = (y + 0.5f) * 0.125f - 0.5f;
  int iy = (int)floorf(sy);
  float fy = sy - iy;
  int y0 = min(27, max(0, iy)), y1 = min(27, max(0, iy + 1));
  const float* p = ps + b * NP;
  if (t < OUTHW) {
    float sx = (t + 0.5f) * 0.125f - 0.5f;
    int ix = (int)floorf(sx);
    float fx = sx - ix;
    int x0 = min(27, max(0, ix)), x1 = min(27, max(0, ix + 1));
    rowbuf[t] = (1.f - fy) * ((1.f - fx) * p[y0 * 28 + x0] + fx * p[y0 * 28 + x1]) +
                fy * ((1.f - fx) * p[y1 * 28 + x0] + fx * p[y1 * 28 + x1]);
  }
  __syncthreads();
  if (t < OUTHW) {
    float s = 0.f;
#pragma unroll
    for (int j = -16; j <= 16; ++j) {
      int x = t + j;
      x = x < 0 ? -x : (x > 223 ? 446 - x : x);
      s += g[j + 16] * rowbuf[x];
    }
    out[(size_t)by * OUTHW + t] = s;
  }
}

// ---------- vertical blur: 16-wide strips (224 blocks, 2x utilization) ----------
__global__ void k_blur_v(const float* __restrict__ in, float* __restrict__ out) {
  int xt = blockIdx.x, b = blockIdx.y, t = threadIdx.x;
  __shared__ float g[33];
  __shared__ float strip[OUTHW][16];
  gauss_coefs(g, t);
  int x0 = xt * 16;
  for (int i = t; i < OUTHW * 16; i += 256) {
    int y = i >> 4, xx = i & 15;
    strip[y][xx] = in[((size_t)b * OUTHW + y) * OUTHW + x0 + xx];
  }
  __syncthreads();
  for (int i = t; i < OUTHW * 16; i += 256) {
    int y = i >> 4, xx = i & 15;
    float s = 0.f;
#pragma unroll
    for (int j = -16; j <= 16; ++j) {
      int yy = y + j;
      yy = yy < 0 ? -yy : (yy > 223 ? 446 - yy : yy);
      s += g[j + 16] * strip[yy][xx];
    }
    out[((size_t)b * OUTHW + y) * OUTHW + x0 + xx] = s;
  }
}

extern "C" void kernel_launch(void* const* d_in, const int* in_sizes, int n_in,
                              void* d_out, int out_size, void* d_ws, size_t ws_size,
                              hipStream_t stream) {
  const float* feat = (const float*)d_in[0];
  const float* mbf = (const float*)d_in[1];
  float* out = (float*)d_out;

  char* ws = (char*)d_ws;
  size_t off = 0;
  auto alloc = [&](size_t bytes) {
    void* p = ws + off;
    off = (off + bytes + 255) & ~(size_t)255;
    return p;
  };
  float* emb = (float*)alloc((size_t)NTOT * DDIM * 4);
  __hip_bfloat16* embh = (__hip_bfloat16*)alloc((size_t)NTOT * DDIM * 2);
  __hip_bfloat16* mbh = (__hip_bfloat16*)alloc((size_t)MTOT * DDIM * 2);
  float* b2 = (float*)alloc(MTOT * 4);
  u64* rowmin = (u64*)alloc(NTOT * 8);
  float* pscore = (float*)alloc(NTOT * 4);
  u64* wrm = (u64*)alloc(NB * 8);
  u64* wmax = (u64*)alloc(NB * 8);
  float* d2nn = (float*)alloc((size_t)NB * MTOT * 4);
  float* amap_tmp = (float*)alloc((size_t)NB * OUTHW * OUTHW * 4);

  k_prep_emb<<<dim3(12, 7, 16), 256, 0, stream>>>(feat, emb, embh);
  k_prep_mb<<<MTOT, 256, 0, stream>>>(mbf, mbh, b2, rowmin, wrm, wmax);
  k_gemm<<<dim3(128, 98), 256, 0, stream>>>(embh, mbh, b2, rowmin);
  k_fixrow<<<NTOT / 4, 256, 0, stream>>>(rowmin, emb, mbf, pscore, wmax);
  k_dist16<0><<<MTOT / 16, 256, 0, stream>>>(mbf, emb, wmax, nullptr, b2, wrm, nullptr);
  k_dist16<1><<<MTOT / 16, 256, 0, stream>>>(mbf, emb, wmax, wrm, b2, nullptr, d2nn);
  k_top9anom<<<NB, 256, 0, stream>>>(d2nn, emb, mbf, wmax, pscore, out + NB * OUTHW * OUTHW);
  k_bh<<<NB * OUTHW, 256, 0, stream>>>(pscore, amap_tmp);
  k_blur_v<<<dim3(14, NB), 256, 0, stream>>>(amap_tmp, out);
}

// Round 17
// 702.090 us; speedup vs baseline: 1.1408x; 1.1408x over previous
//
#include <hip/hip_runtime.h>
#include <hip/hip_bf16.h>

#define NB 16
#define DDIM 768
#define HH 28
#define WWID 28
#define NP 784
#define NTOT 12544
#define MTOT 16384
#define OUTHW 224

typedef __attribute__((ext_vector_type(8))) short bf16x8;
typedef __attribute__((ext_vector_type(4))) float f32x4;
typedef unsigned long long u64;

__device__ inline u64 packmin(float v, int idx) {
  unsigned u = __float_as_uint(v);
  u = (u & 0x80000000u) ? ~u : (u | 0x80000000u);
  return ((u64)u << 32) | (unsigned)idx;
}
__device__ inline float unpackval(u64 p) {
  unsigned hi = (unsigned)(p >> 32);
  return (hi & 0x80000000u) ? __uint_as_float(hi ^ 0x80000000u) : __uint_as_float(~hi);
}

__device__ inline void gload16(const void* g, void* l) {
  __builtin_amdgcn_global_load_lds((const __attribute__((address_space(1))) unsigned int*)g,
                                   (__attribute__((address_space(3))) unsigned int*)l, 16, 0, 0);
}

// ---------- memory bank: bf16 + norms (+ rowmin/a2 zero-init folded in) ----------
// Launched FIRST so a2 is zeroed before k_prep_emb accumulates into it.
__global__ void k_prep_mb(const float* __restrict__ mb, __hip_bfloat16* __restrict__ mbh,
                          float* __restrict__ b2, u64* __restrict__ rowmin,
                          float* __restrict__ a2) {
  int m = blockIdx.x, t = threadIdx.x;
  if (t == 0 && m < NTOT) { rowmin[m] = ~0ull; a2[m] = 0.f; }
  const float* r = mb + (size_t)m * DDIM;
  float s = 0.f;
#pragma unroll
  for (int j = 0; j < 3; ++j) {
    float v = r[t + j * 256];
    s += v * v;
    mbh[(size_t)m * DDIM + t + j * 256] = __float2bfloat16(v);
  }
  for (int o = 32; o; o >>= 1) s += __shfl_down(s, o);
  __shared__ float ws4[4];
  if ((t & 63) == 0) ws4[t >> 6] = s;
  __syncthreads();
  if (t == 0) b2[m] = ws4[0] + ws4[1] + ws4[2] + ws4[3];
}

// ---------- avgpool3x3 + transpose to [N,D] + bf16 + a2 partials ----------
__global__ void k_prep_emb(const float* __restrict__ feat,
                           __hip_bfloat16* __restrict__ embh, float* __restrict__ emb,
                           float* __restrict__ a2) {
  const int dt = blockIdx.x;   // 12
  const int ht = blockIdx.y;   // 7
  const int b  = blockIdx.z;   // 16
  const int d0 = dt * 64;
  const int h0 = ht * 4;
  const int n0 = b * NP + ht * 112;
  __shared__ float halo[64][169];
  __shared__ float a2s[112];
  const int t = threadIdx.x;
  for (int i = t; i < 112; i += 256) a2s[i] = 0.f;
  for (int idx = t; idx < 64 * 168; idx += 256) {
    int dd = idx / 168, p = idx % 168;
    int rr = p / 28, w = p % 28;
    int h = h0 - 1 + rr;
    float v = 0.f;
    if (h >= 0 && h < HH)
      v = feat[(((size_t)b * DDIM + d0 + dd) * HH + h) * WWID + w];
    halo[dd][p] = v;
  }
  __syncthreads();
  for (int idx = t; idx < 112 * 64; idx += 256) {
    int nn = idx >> 6, dd = idx & 63;
    int hl = nn / 28, w = nn % 28;
    float s = 0.f;
#pragma unroll
    for (int dr = 0; dr < 3; ++dr) {
      const float* row = &halo[dd][(hl + dr) * 28];
      float c = row[w];
      if (w > 0) c += row[w - 1];
      if (w < 27) c += row[w + 1];
      s += c;
    }
    float v = s * (1.f / 9.f);
    size_t o = (size_t)(n0 + nn) * DDIM + d0 + dd;
    emb[o] = v;
    embh[o] = __float2bfloat16(v);
    // nn is wave-uniform (dd == lane): shuffle-reduce, single writer per wave
    float vv = v * v;
    for (int off = 32; off; off >>= 1) vv += __shfl_down(vv, off);
    if ((t & 63) == 0) a2s[nn] += vv;
  }
  __syncthreads();
  for (int i = t; i < 112; i += 256) atomicAdd(&a2[n0 + i], a2s[i]);
}

// ============ GEMM: R13 verbatim — 128x128, BK=32, single-buffer, 2 syncs,
// ============ coalesced staging, in-row XOR swizzle (0 conflicts), 14 waves/CU.
__global__ __launch_bounds__(256) void k_gemm(const __hip_bfloat16* __restrict__ A,
                                              const __hip_bfloat16* __restrict__ Bm,
                                              const float* __restrict__ b2,
                                              u64* __restrict__ rowmin) {
  __shared__ short As[128 * 32];
  __shared__ short Bs[128 * 32];
  __shared__ u64 rmin[128][2];
  const int t = threadIdx.x;
  const int m0 = blockIdx.x * 128;
  const int n0 = blockIdx.y * 128;
  const int w = t >> 6, l = t & 63;
  const int wr = w >> 1, wc = w & 1;
  const int lc = l & 15, lg = l >> 4;
  const int swz = lg ^ ((lc >> 1) & 3);   // fragment-read slot column

  const int s0 = t, s1 = t + 256;
  const int row0 = s0 >> 2, ko0 = (s0 & 3) ^ ((row0 >> 1) & 3);
  const int row1 = s1 >> 2, ko1 = (s1 & 3) ^ ((row1 >> 1) & 3);
  const __hip_bfloat16* Asrc0 = A + (size_t)(n0 + row0) * DDIM + ko0 * 8;
  const __hip_bfloat16* Asrc1 = A + (size_t)(n0 + row1) * DDIM + ko1 * 8;
  const __hip_bfloat16* Bsrc0 = Bm + (size_t)(m0 + row0) * DDIM + ko0 * 8;
  const __hip_bfloat16* Bsrc1 = Bm + (size_t)(m0 + row1) * DDIM + ko1 * 8;

  f32x4 acc[4][4] = {};
  for (int kt = 0; kt < 24; ++kt) {
    const int k0 = kt * 32;
    __syncthreads();
    gload16(Asrc0 + k0, (char*)As + s0 * 16);
    gload16(Bsrc0 + k0, (char*)Bs + s0 * 16);
    gload16(Asrc1 + k0, (char*)As + s1 * 16);
    gload16(Bsrc1 + k0, (char*)Bs + s1 * 16);
    __syncthreads();
    bf16x8 av[4], bv[4];
#pragma unroll
    for (int i = 0; i < 4; ++i) {
      av[i] = *(const bf16x8*)(As + (wr * 64 + i * 16 + lc) * 32 + swz * 8);
      bv[i] = *(const bf16x8*)(Bs + (wc * 64 + i * 16 + lc) * 32 + swz * 8);
    }
#pragma unroll
    for (int i = 0; i < 4; ++i)
#pragma unroll
      for (int j = 0; j < 4; ++j)
        acc[i][j] = __builtin_amdgcn_mfma_f32_16x16x32_bf16(av[i], bv[j], acc[i][j], 0, 0, 0);
  }
  __syncthreads();
  float b2v[4];
#pragma unroll
  for (int j = 0; j < 4; ++j) b2v[j] = b2[m0 + wc * 64 + j * 16 + lc];
#pragma unroll
  for (int i = 0; i < 4; ++i)
#pragma unroll
    for (int r = 0; r < 4; ++r) {
      u64 best = ~0ull;
#pragma unroll
      for (int j = 0; j < 4; ++j) {
        int col = m0 + wc * 64 + j * 16 + lc;
        float v = b2v[j] - 2.f * acc[i][j][r];
        u64 p = packmin(v, col);
        best = best < p ? best : p;
      }
#pragma unroll
      for (int o = 1; o < 16; o <<= 1) {
        u64 o2 = (u64)__shfl_xor((long long)best, o);
        best = best < o2 ? best : o2;
      }
      if (lc == 0) rmin[wr * 64 + i * 16 + lg * 4 + r][wc] = best;
    }
  __syncthreads();
  if (t < 128) {
    u64 b0 = rmin[t][0], b1 = rmin[t][1];
    u64 mm = b0 < b1 ? b0 : b1;
    atomicMin(&rowmin[n0 + t], mm);
  }
}

// ---------- patch scores directly from packed min (R1 scheme, no row recompute) ----------
__global__ void k_scores(const u64* __restrict__ rowmin, const float* __restrict__ a2,
                         float* __restrict__ ps) {
  int n = blockIdx.x * 256 + threadIdx.x;
  if (n >= NTOT) return;
  float d2 = a2[n] + unpackval(rowmin[n]);
  ps[n] = sqrtf(fmaxf(d2, 0.f));
}

// ---------- per-batch argmax patch (+ wrm init) ----------
__global__ void k_topc(const float* __restrict__ ps, int* __restrict__ wn,
                       u64* __restrict__ wrm) {
  int b = blockIdx.x, t = threadIdx.x;
  if (t == 0) wrm[b] = ~0ull;
  float bv = -1e30f; int bi = 1 << 30;
  for (int i = t; i < NP; i += 256) {
    float v = ps[b * NP + i];
    if (v > bv || (v == bv && i < bi)) { bv = v; bi = i; }
  }
  __shared__ float rv[256];
  __shared__ int ri[256];
  rv[t] = bv; ri[t] = bi;
  __syncthreads();
  for (int s = 128; s; s >>= 1) {
    if (t < s) {
      if (rv[t + s] > rv[t] || (rv[t + s] == rv[t] && ri[t + s] < ri[t])) {
        rv[t] = rv[t + s]; ri[t] = ri[t + s];
      }
    }
    __syncthreads();
  }
  if (t == 0) wn[b] = b * NP + ri[0];
}

// ---------- 16 query rows vs all M, fp32, padded-LDS (conflict-free) ----------
template <int MODE>
__global__ void k_dist16(const float* __restrict__ mbf, const float* __restrict__ emb,
                         const int* __restrict__ wn, const u64* __restrict__ wrm_in,
                         const float* __restrict__ b2,
                         u64* __restrict__ wrm_out, float* __restrict__ d2nn) {
  __shared__ float qr[16][66];
  __shared__ float mr[16][65];
  __shared__ int qi[16];
  int t = threadIdx.x;
  int m0 = blockIdx.x * 16;
  if (t < 16) qi[t] = (MODE == 0) ? wn[t] : (int)(wrm_in[t] & 0xffffffffu);
  __syncthreads();
  int b = t >> 4, mi = t & 15;
  float acc = 0.f;
  const float* qsrc = (MODE == 0) ? emb : mbf;
  for (int k0 = 0; k0 < DDIM; k0 += 64) {
    __syncthreads();
    for (int i = t; i < 1024; i += 256) {
      int r = i >> 6, kk = i & 63;
      qr[r][kk] = qsrc[(size_t)qi[r] * DDIM + k0 + kk];
      mr[r][kk] = mbf[(size_t)(m0 + r) * DDIM + k0 + kk];
    }
    __syncthreads();
#pragma unroll
    for (int kk = 0; kk < 64; ++kk) acc += qr[b][kk] * mr[mi][kk];
  }
  int m = m0 + mi;
  if (MODE == 0) {
    u64 p = packmin(b2[m] - 2.f * acc, m);
#pragma unroll
    for (int o = 1; o < 16; o <<= 1) {
      u64 o2 = (u64)__shfl_xor((long long)p, o);
      p = p < o2 ? p : o2;
    }
    if (mi == 0) atomicMin(&wrm_out[b], p);
  } else {
    d2nn[(size_t)b * MTOT + m] = b2[qi[b]] + b2[m] - 2.f * acc;
  }
}

// ---------- top-9 nearest + anomaly score (fused, register-cached row) ----------
__global__ void k_top9anom(const float* __restrict__ d2nn, const float* __restrict__ emb,
                           const float* __restrict__ mbf, const int* __restrict__ wn,
                           const float* __restrict__ ps, float* __restrict__ out_anom) {
  int b = blockIdx.x, t = threadIdx.x;
  const float* row = d2nn + (size_t)b * MTOT;
  float rvreg[64];
#pragma unroll
  for (int it = 0; it < 64; ++it) rvreg[it] = row[t + it * 256];
  __shared__ u64 red[256];
  __shared__ int chosen[9];
  for (int k = 0; k < 9; ++k) {
    u64 best = ~0ull;
#pragma unroll
    for (int it = 0; it < 64; ++it) {
      int m = t + it * 256;
      bool skip = false;
      for (int j = 0; j < k; ++j)
        if (chosen[j] == m) skip = true;
      if (!skip) {
        u64 p = packmin(rvreg[it], m);
        best = best < p ? best : p;
      }
    }
    red[t] = best; __syncthreads();
    for (int s = 128; s; s >>= 1) {
      if (t < s) red[t] = red[t] < red[t + s] ? red[t] : red[t + s];
      __syncthreads();
    }
    if (t == 0) chosen[k] = (int)(red[0] & 0xffffffffu);
    __syncthreads();
  }
  __shared__ float er[DDIM];
  __shared__ float dist[9];
  __shared__ float fred[256];
  for (int j = t; j < DDIM; j += 256) er[j] = emb[(size_t)wn[b] * DDIM + j];
  __syncthreads();
  for (int k = 0; k < 9; ++k) {
    const float* mr = mbf + (size_t)chosen[k] * DDIM;
    float s = 0.f;
    for (int j = t; j < DDIM; j += 256) { float d = er[j] - mr[j]; s += d * d; }
    fred[t] = s; __syncthreads();
    for (int st = 128; st; st >>= 1) { if (t < st) fred[t] += fred[t + st]; __syncthreads(); }
    if (t == 0) dist[k] = sqrtf(fmaxf(fred[0], 0.f));
    __syncthreads();
  }
  if (t == 0) {
    float mx = dist[0];
    for (int k = 1; k < 9; ++k) mx = fmaxf(mx, dist[k]);
    float sum = 0.f;
    for (int k = 0; k < 9; ++k) sum += expf(dist[k] - mx);
    float w = 1.f - expf(dist[0] - mx) / sum;
    out_anom[b] = w * ps[wn[b]];
  }
}

__device__ inline void gauss_coefs(float* g, int t) {
  if (t == 0) {
    float tmp[33]; float s = 0.f;
    for (int j = 0; j < 33; ++j) { float c = (float)(j - 16); tmp[j] = expf(-(c * c) / 32.f); s += tmp[j]; }
    for (int j = 0; j < 33; ++j) g[j] = tmp[j] / s;
  }
}

// ---------- fused bilinear 28->224 (row) + horizontal gaussian blur ----------
__global__ void k_bh(const float* __restrict__ ps, float* __restrict__ out) {
  int by = blockIdx.x;  // b*224 + y
  int b = by / OUTHW, y = by % OUTHW;
  int t = threadIdx.x;
  __shared__ float g[33];
  __shared__ float rowbuf[OUTHW];
  gauss_coefs(g, t);
  float sy = (y + 0.5f) * 0.125f - 0.5f;
  int iy = (int)floorf(sy);
  float fy = sy - iy;
  int y0 = min(27, max(0, iy)), y1 = min(27, max(0, iy + 1));
  const float* p = ps + b * NP;
  if (t < OUTHW) {
    float sx = (t + 0.5f) * 0.125f - 0.5f;
    int ix = (int)floorf(sx);
    float fx = sx - ix;
    int x0 = min(27, max(0, ix)), x1 = min(27, max(0, ix + 1));
    rowbuf[t] = (1.f - fy) * ((1.f - fx) * p[y0 * 28 + x0] + fx * p[y0 * 28 + x1]) +
                fy * ((1.f - fx) * p[y1 * 28 + x0] + fx * p[y1 * 28 + x1]);
  }
  __syncthreads();
  if (t < OUTHW) {
    float s = 0.f;
#pragma unroll
    for (int j = -16; j <= 16; ++j) {
      int x = t + j;
      x = x < 0 ? -x : (x > 223 ? 446 - x : x);
      s += g[j + 16] * rowbuf[x];
    }
    out[(size_t)by * OUTHW + t] = s;
  }
}

__global__ void k_blur_v(const float* __restrict__ in, float* __restrict__ out) {
  int xt = blockIdx.x, b = blockIdx.y, t = threadIdx.x;
  __shared__ float g[33];
  __shared__ float strip[OUTHW][32];
  gauss_coefs(g, t);
  int x0 = xt * 32;
  for (int i = t; i < OUTHW * 32; i += 256) {
    int y = i >> 5, xx = i & 31;
    strip[y][xx] = in[((size_t)b * OUTHW + y) * OUTHW + x0 + xx];
  }
  __syncthreads();
  for (int i = t; i < OUTHW * 32; i += 256) {
    int y = i >> 5, xx = i & 31;
    float s = 0.f;
#pragma unroll
    for (int j = -16; j <= 16; ++j) {
      int yy = y + j;
      yy = yy < 0 ? -yy : (yy > 223 ? 446 - yy : yy);
      s += g[j + 16] * strip[yy][xx];
    }
    out[((size_t)b * OUTHW + y) * OUTHW + x0 + xx] = s;
  }
}

extern "C" void kernel_launch(void* const* d_in, const int* in_sizes, int n_in,
                              void* d_out, int out_size, void* d_ws, size_t ws_size,
                              hipStream_t stream) {
  const float* feat = (const float*)d_in[0];
  const float* mbf = (const float*)d_in[1];
  float* out = (float*)d_out;

  char* ws = (char*)d_ws;
  size_t off = 0;
  auto alloc = [&](size_t bytes) {
    void* p = ws + off;
    off = (off + bytes + 255) & ~(size_t)255;
    return p;
  };
  float* emb = (float*)alloc((size_t)NTOT * DDIM * 4);
  __hip_bfloat16* embh = (__hip_bfloat16*)alloc((size_t)NTOT * DDIM * 2);
  __hip_bfloat16* mbh = (__hip_bfloat16*)alloc((size_t)MTOT * DDIM * 2);
  float* b2 = (float*)alloc(MTOT * 4);
  float* a2 = (float*)alloc(NTOT * 4);
  u64* rowmin = (u64*)alloc(NTOT * 8);
  float* pscore = (float*)alloc(NTOT * 4);
  int* wn = (int*)alloc(NB * 4);
  u64* wrm = (u64*)alloc(NB * 8);
  float* d2nn = (float*)alloc((size_t)NB * MTOT * 4);
  float* amap_tmp = (float*)alloc((size_t)NB * OUTHW * OUTHW * 4);

  k_prep_mb<<<MTOT, 256, 0, stream>>>(mbf, mbh, b2, rowmin, a2);
  k_prep_emb<<<dim3(12, 7, 16), 256, 0, stream>>>(feat, embh, emb, a2);
  k_gemm<<<dim3(128, 98), 256, 0, stream>>>(embh, mbh, b2, rowmin);
  k_scores<<<49, 256, 0, stream>>>(rowmin, a2, pscore);
  k_topc<<<NB, 256, 0, stream>>>(pscore, wn, wrm);
  k_dist16<0><<<MTOT / 16, 256, 0, stream>>>(mbf, emb, wn, nullptr, b2, wrm, nullptr);
  k_dist16<1><<<MTOT / 16, 256, 0, stream>>>(mbf, emb, wn, wrm, b2, nullptr, d2nn);
  k_top9anom<<<NB, 256, 0, stream>>>(d2nn, emb, mbf, wn, pscore, out + NB * OUTHW * OUTHW);
  k_bh<<<NB * OUTHW, 256, 0, stream>>>(pscore, amap_tmp);
  k_blur_v<<<dim3(7, NB), 256, 0, stream>>>(amap_tmp, out);
}

// Round 18
// 649.383 us; speedup vs baseline: 1.2334x; 1.0812x over previous
//
#include <hip/hip_runtime.h>
#include <hip/hip_bf16.h>

#define NB 16
#define DDIM 768
#define HH 28
#define WWID 28
#define NP 784
#define NTOT 12544
#define MTOT 16384
#define OUTHW 224

typedef __attribute__((ext_vector_type(8))) short bf16x8;
typedef __attribute__((ext_vector_type(4))) float f32x4;
typedef unsigned long long u64;

__device__ inline u64 packmin(float v, int idx) {
  unsigned u = __float_as_uint(v);
  u = (u & 0x80000000u) ? ~u : (u | 0x80000000u);
  return ((u64)u << 32) | (unsigned)idx;
}
__device__ inline float unpackval(u64 p) {
  unsigned hi = (unsigned)(p >> 32);
  return (hi & 0x80000000u) ? __uint_as_float(hi ^ 0x80000000u) : __uint_as_float(~hi);
}

__device__ inline void gload16(const void* g, void* l) {
  __builtin_amdgcn_global_load_lds((const __attribute__((address_space(1))) unsigned int*)g,
                                   (__attribute__((address_space(3))) unsigned int*)l, 16, 0, 0);
}

// ---------- memory bank: bf16 + norms (+ rowmin init folded in) ----------
__global__ void k_prep_mb(const float* __restrict__ mb, __hip_bfloat16* __restrict__ mbh,
                          float* __restrict__ b2, u64* __restrict__ rowmin) {
  int m = blockIdx.x, t = threadIdx.x;
  if (t == 0 && m < NTOT) rowmin[m] = ~0ull;
  const float* r = mb + (size_t)m * DDIM;
  float s = 0.f;
#pragma unroll
  for (int j = 0; j < 3; ++j) {
    float v = r[t + j * 256];
    s += v * v;
    mbh[(size_t)m * DDIM + t + j * 256] = __float2bfloat16(v);
  }
  for (int o = 32; o; o >>= 1) s += __shfl_down(s, o);
  __shared__ float ws4[4];
  if ((t & 63) == 0) ws4[t >> 6] = s;
  __syncthreads();
  if (t == 0) b2[m] = ws4[0] + ws4[1] + ws4[2] + ws4[3];
}

// ---------- avgpool3x3 + transpose to [N,D] + fp32 & bf16 ----------
__global__ void k_prep_emb(const float* __restrict__ feat, float* __restrict__ emb,
                           __hip_bfloat16* __restrict__ embh) {
  const int dt = blockIdx.x;   // 12
  const int ht = blockIdx.y;   // 7
  const int b  = blockIdx.z;   // 16
  const int d0 = dt * 64;
  const int h0 = ht * 4;
  const int n0 = b * NP + ht * 112;
  __shared__ float halo[64][169];
  const int t = threadIdx.x;
  for (int idx = t; idx < 64 * 168; idx += 256) {
    int dd = idx / 168, p = idx % 168;
    int rr = p / 28, w = p % 28;
    int h = h0 - 1 + rr;
    float v = 0.f;
    if (h >= 0 && h < HH)
      v = feat[(((size_t)b * DDIM + d0 + dd) * HH + h) * WWID + w];
    halo[dd][p] = v;
  }
  __syncthreads();
  for (int idx = t; idx < 112 * 64; idx += 256) {
    int nn = idx >> 6, dd = idx & 63;
    int hl = nn / 28, w = nn % 28;
    float s = 0.f;
#pragma unroll
    for (int dr = 0; dr < 3; ++dr) {
      const float* row = &halo[dd][(hl + dr) * 28];
      float c = row[w];
      if (w > 0) c += row[w - 1];
      if (w < 27) c += row[w + 1];
      s += c;
    }
    float v = s * (1.f / 9.f);
    size_t o = (size_t)(n0 + nn) * DDIM + d0 + dd;
    emb[o] = v;
    embh[o] = __float2bfloat16(v);
  }
}

// ============ GEMM: R13 verbatim — 128x128, BK=32, single-buffer, 2 syncs,
// ============ coalesced staging, in-row XOR swizzle (0 conflicts), 14 waves/CU.
__global__ __launch_bounds__(256) void k_gemm(const __hip_bfloat16* __restrict__ A,
                                              const __hip_bfloat16* __restrict__ Bm,
                                              const float* __restrict__ b2,
                                              u64* __restrict__ rowmin) {
  __shared__ short As[128 * 32];
  __shared__ short Bs[128 * 32];
  __shared__ u64 rmin[128][2];
  const int t = threadIdx.x;
  const int m0 = blockIdx.x * 128;
  const int n0 = blockIdx.y * 128;
  const int w = t >> 6, l = t & 63;
  const int wr = w >> 1, wc = w & 1;
  const int lc = l & 15, lg = l >> 4;
  const int swz = lg ^ ((lc >> 1) & 3);   // fragment-read slot column

  const int s0 = t, s1 = t + 256;
  const int row0 = s0 >> 2, ko0 = (s0 & 3) ^ ((row0 >> 1) & 3);
  const int row1 = s1 >> 2, ko1 = (s1 & 3) ^ ((row1 >> 1) & 3);
  const __hip_bfloat16* Asrc0 = A + (size_t)(n0 + row0) * DDIM + ko0 * 8;
  const __hip_bfloat16* Asrc1 = A + (size_t)(n0 + row1) * DDIM + ko1 * 8;
  const __hip_bfloat16* Bsrc0 = Bm + (size_t)(m0 + row0) * DDIM + ko0 * 8;
  const __hip_bfloat16* Bsrc1 = Bm + (size_t)(m0 + row1) * DDIM + ko1 * 8;

  f32x4 acc[4][4] = {};
  for (int kt = 0; kt < 24; ++kt) {
    const int k0 = kt * 32;
    __syncthreads();
    gload16(Asrc0 + k0, (char*)As + s0 * 16);
    gload16(Bsrc0 + k0, (char*)Bs + s0 * 16);
    gload16(Asrc1 + k0, (char*)As + s1 * 16);
    gload16(Bsrc1 + k0, (char*)Bs + s1 * 16);
    __syncthreads();
    bf16x8 av[4], bv[4];
#pragma unroll
    for (int i = 0; i < 4; ++i) {
      av[i] = *(const bf16x8*)(As + (wr * 64 + i * 16 + lc) * 32 + swz * 8);
      bv[i] = *(const bf16x8*)(Bs + (wc * 64 + i * 16 + lc) * 32 + swz * 8);
    }
#pragma unroll
    for (int i = 0; i < 4; ++i)
#pragma unroll
      for (int j = 0; j < 4; ++j)
        acc[i][j] = __builtin_amdgcn_mfma_f32_16x16x32_bf16(av[i], bv[j], acc[i][j], 0, 0, 0);
  }
  __syncthreads();
  float b2v[4];
#pragma unroll
  for (int j = 0; j < 4; ++j) b2v[j] = b2[m0 + wc * 64 + j * 16 + lc];
#pragma unroll
  for (int i = 0; i < 4; ++i)
#pragma unroll
    for (int r = 0; r < 4; ++r) {
      u64 best = ~0ull;
#pragma unroll
      for (int j = 0; j < 4; ++j) {
        int col = m0 + wc * 64 + j * 16 + lc;
        float v = b2v[j] - 2.f * acc[i][j][r];
        u64 p = packmin(v, col);
        best = best < p ? best : p;
      }
#pragma unroll
      for (int o = 1; o < 16; o <<= 1) {
        u64 o2 = (u64)__shfl_xor((long long)best, o);
        best = best < o2 ? best : o2;
      }
      if (lc == 0) rmin[wr * 64 + i * 16 + lg * 4 + r][wc] = best;
    }
  __syncthreads();
  if (t < 128) {
    u64 b0 = rmin[t][0], b1 = rmin[t][1];
    u64 mm = b0 < b1 ? b0 : b1;
    atomicMin(&rowmin[n0 + t], mm);
  }
}

// ---------- patch scores: a2 computed inline (wave per row) + packed min ----------
__global__ void k_scores(const u64* __restrict__ rowmin, const float* __restrict__ emb,
                         float* __restrict__ ps) {
  int n = blockIdx.x * 4 + (threadIdx.x >> 6);
  int lane = threadIdx.x & 63;
  const float* e = emb + (size_t)n * DDIM;
  float s = 0.f;
#pragma unroll
  for (int j = lane; j < DDIM; j += 64) { float v = e[j]; s += v * v; }
  for (int o = 32; o; o >>= 1) s += __shfl_down(s, o);
  if (lane == 0) {
    float d2 = s + unpackval(rowmin[n]);
    ps[n] = sqrtf(fmaxf(d2, 0.f));
  }
}

// ---------- per-batch argmax patch ----------
__global__ void k_topc(const float* __restrict__ ps, int* __restrict__ wn) {
  int b = blockIdx.x, t = threadIdx.x;
  float bv = -1e30f; int bi = 1 << 30;
  for (int i = t; i < NP; i += 256) {
    float v = ps[b * NP + i];
    if (v > bv || (v == bv && i < bi)) { bv = v; bi = i; }
  }
  __shared__ float rv[256];
  __shared__ int ri[256];
  rv[t] = bv; ri[t] = bi;
  __syncthreads();
  for (int s = 128; s; s >>= 1) {
    if (t < s) {
      if (rv[t + s] > rv[t] || (rv[t + s] == rv[t] && ri[t + s] < ri[t])) {
        rv[t] = rv[t + s]; ri[t] = ri[t + s];
      }
    }
    __syncthreads();
  }
  if (t == 0) wn[b] = b * NP + ri[0];
}

// ---------- d2 rows: nn_sample (= mb[rowmin[wn]&mask]) vs all M, fp32, padded LDS ----------
__global__ void k_d2nn(const float* __restrict__ mbf, const int* __restrict__ wn,
                       const u64* __restrict__ rowmin, const float* __restrict__ b2,
                       float* __restrict__ d2nn) {
  __shared__ float qr[16][66];
  __shared__ float mr[16][65];
  __shared__ int qi[16];
  int t = threadIdx.x;
  int m0 = blockIdx.x * 16;
  if (t < 16) qi[t] = (int)(rowmin[wn[t]] & 0xffffffffu);
  __syncthreads();
  int b = t >> 4, mi = t & 15;
  float acc = 0.f;
  for (int k0 = 0; k0 < DDIM; k0 += 64) {
    __syncthreads();
    for (int i = t; i < 1024; i += 256) {
      int r = i >> 6, kk = i & 63;
      qr[r][kk] = mbf[(size_t)qi[r] * DDIM + k0 + kk];
      mr[r][kk] = mbf[(size_t)(m0 + r) * DDIM + k0 + kk];
    }
    __syncthreads();
#pragma unroll
    for (int kk = 0; kk < 64; ++kk) acc += qr[b][kk] * mr[mi][kk];
  }
  int m = m0 + mi;
  d2nn[(size_t)b * MTOT + m] = b2[qi[b]] + b2[m] - 2.f * acc;
}

// ---------- top-9 nearest + anomaly score (fused, register-cached row) ----------
__global__ void k_top9anom(const float* __restrict__ d2nn, const float* __restrict__ emb,
                           const float* __restrict__ mbf, const int* __restrict__ wn,
                           const float* __restrict__ ps, float* __restrict__ out_anom) {
  int b = blockIdx.x, t = threadIdx.x;
  const float* row = d2nn + (size_t)b * MTOT;
  float rvreg[64];
#pragma unroll
  for (int it = 0; it < 64; ++it) rvreg[it] = row[t + it * 256];
  __shared__ u64 red[256];
  __shared__ int chosen[9];
  for (int k = 0; k < 9; ++k) {
    u64 best = ~0ull;
#pragma unroll
    for (int it = 0; it < 64; ++it) {
      int m = t + it * 256;
      bool skip = false;
      for (int j = 0; j < k; ++j)
        if (chosen[j] == m) skip = true;
      if (!skip) {
        u64 p = packmin(rvreg[it], m);
        best = best < p ? best : p;
      }
    }
    red[t] = best; __syncthreads();
    for (int s = 128; s; s >>= 1) {
      if (t < s) red[t] = red[t] < red[t + s] ? red[t] : red[t + s];
      __syncthreads();
    }
    if (t == 0) chosen[k] = (int)(red[0] & 0xffffffffu);
    __syncthreads();
  }
  __shared__ float er[DDIM];
  __shared__ float dist[9];
  __shared__ float fred[256];
  for (int j = t; j < DDIM; j += 256) er[j] = emb[(size_t)wn[b] * DDIM + j];
  __syncthreads();
  for (int k = 0; k < 9; ++k) {
    const float* mr = mbf + (size_t)chosen[k] * DDIM;
    float s = 0.f;
    for (int j = t; j < DDIM; j += 256) { float d = er[j] - mr[j]; s += d * d; }
    fred[t] = s; __syncthreads();
    for (int st = 128; st; st >>= 1) { if (t < st) fred[t] += fred[t + st]; __syncthreads(); }
    if (t == 0) dist[k] = sqrtf(fmaxf(fred[0], 0.f));
    __syncthreads();
  }
  if (t == 0) {
    float mx = dist[0];
    for (int k = 1; k < 9; ++k) mx = fmaxf(mx, dist[k]);
    float sum = 0.f;
    for (int k = 0; k < 9; ++k) sum += expf(dist[k] - mx);
    float w = 1.f - expf(dist[0] - mx) / sum;
    out_anom[b] = w * ps[wn[b]];
  }
}

__device__ inline void gauss_coefs(float* g, int t) {
  if (t == 0) {
    float tmp[33]; float s = 0.f;
    for (int j = 0; j < 33; ++j) { float c = (float)(j - 16); tmp[j] = expf(-(c * c) / 32.f); s += tmp[j]; }
    for (int j = 0; j < 33; ++j) g[j] = tmp[j] / s;
  }
}

// ---------- fused bilinear 28->224 (row) + horizontal gaussian blur ----------
__global__ void k_bh(const float* __restrict__ ps, float* __restrict__ out) {
  int by = blockIdx.x;  // b*224 + y
  int b = by / OUTHW, y = by % OUTHW;
  int t = threadIdx.x;
  __shared__ float g[33];
  __shared__ float rowbuf[OUTHW];
  gauss_coefs(g, t);
  float sy = (y + 0.5f) * 0.125f - 0.5f;
  int iy = (int)floorf(sy);
  float fy = sy - iy;
  int y0 = min(27, max(0, iy)), y1 = min(27, max(0, iy + 1));
  const float* p = ps + b * NP;
  if (t < OUTHW) {
    float sx = (t + 0.5f) * 0.125f - 0.5f;
    int ix = (int)floorf(sx);
    float fx = sx - ix;
    int x0 = min(27, max(0, ix)), x1 = min(27, max(0, ix + 1));
    rowbuf[t] = (1.f - fy) * ((1.f - fx) * p[y0 * 28 + x0] + fx * p[y0 * 28 + x1]) +
                fy * ((1.f - fx) * p[y1 * 28 + x0] + fx * p[y1 * 28 + x1]);
  }
  __syncthreads();
  if (t < OUTHW) {
    float s = 0.f;
#pragma unroll
    for (int j = -16; j <= 16; ++j) {
      int x = t + j;
      x = x < 0 ? -x : (x > 223 ? 446 - x : x);
      s += g[j + 16] * rowbuf[x];
    }
    out[(size_t)by * OUTHW + t] = s;
  }
}

__global__ void k_blur_v(const float* __restrict__ in, float* __restrict__ out) {
  int xt = blockIdx.x, b = blockIdx.y, t = threadIdx.x;
  __shared__ float g[33];
  __shared__ float strip[OUTHW][32];
  gauss_coefs(g, t);
  int x0 = xt * 32;
  for (int i = t; i < OUTHW * 32; i += 256) {
    int y = i >> 5, xx = i & 31;
    strip[y][xx] = in[((size_t)b * OUTHW + y) * OUTHW + x0 + xx];
  }
  __syncthreads();
  for (int i = t; i < OUTHW * 32; i += 256) {
    int y = i >> 5, xx = i & 31;
    float s = 0.f;
#pragma unroll
    for (int j = -16; j <= 16; ++j) {
      int yy = y + j;
      yy = yy < 0 ? -yy : (yy > 223 ? 446 - yy : yy);
      s += g[j + 16] * strip[yy][xx];
    }
    out[((size_t)b * OUTHW + y) * OUTHW + x0 + xx] = s;
  }
}

extern "C" void kernel_launch(void* const* d_in, const int* in_sizes, int n_in,
                              void* d_out, int out_size, void* d_ws, size_t ws_size,
                              hipStream_t stream) {
  const float* feat = (const float*)d_in[0];
  const float* mbf = (const float*)d_in[1];
  float* out = (float*)d_out;

  char* ws = (char*)d_ws;
  size_t off = 0;
  auto alloc = [&](size_t bytes) {
    void* p = ws + off;
    off = (off + bytes + 255) & ~(size_t)255;
    return p;
  };
  float* emb = (float*)alloc((size_t)NTOT * DDIM * 4);
  __hip_bfloat16* embh = (__hip_bfloat16*)alloc((size_t)NTOT * DDIM * 2);
  __hip_bfloat16* mbh = (__hip_bfloat16*)alloc((size_t)MTOT * DDIM * 2);
  float* b2 = (float*)alloc(MTOT * 4);
  u64* rowmin = (u64*)alloc(NTOT * 8);
  float* pscore = (float*)alloc(NTOT * 4);
  int* wn = (int*)alloc(NB * 4);
  float* d2nn = (float*)alloc((size_t)NB * MTOT * 4);
  float* amap_tmp = (float*)alloc((size_t)NB * OUTHW * OUTHW * 4);

  k_prep_mb<<<MTOT, 256, 0, stream>>>(mbf, mbh, b2, rowmin);
  k_prep_emb<<<dim3(12, 7, 16), 256, 0, stream>>>(feat, emb, embh);
  k_gemm<<<dim3(128, 98), 256, 0, stream>>>(embh, mbh, b2, rowmin);
  k_scores<<<NTOT / 4, 256, 0, stream>>>(rowmin, emb, pscore);
  k_topc<<<NB, 256, 0, stream>>>(pscore, wn);
  k_d2nn<<<MTOT / 16, 256, 0, stream>>>(mbf, wn, rowmin, b2, d2nn);
  k_top9anom<<<NB, 256, 0, stream>>>(d2nn, emb, mbf, wn, pscore, out + NB * OUTHW * OUTHW);
  k_bh<<<NB * OUTHW, 256, 0, stream>>>(pscore, amap_tmp);
  k_blur_v<<<dim3(7, NB), 256, 0, stream>>>(amap_tmp, out);
}